// Round 1
// baseline (221.735 us; speedup 1.0000x reference)
//
#include <hip/hip_runtime.h>

#define TEX_W 2048
#define TEX_H 2048

__global__ __launch_bounds__(256) void difftex_bilinear_kernel(
    const float* __restrict__ uvs,
    const float* __restrict__ tex,
    float* __restrict__ out,
    int n)
{
    int i = blockIdx.x * blockDim.x + threadIdx.x;
    if (i >= n) return;

    // coalesced 8B/lane load of (u,v)
    float2 uv = reinterpret_cast<const float2*>(uvs)[i];

    // map [-1,1] -> [0, dim-1] texel coords, exactly as reference
    float u = (uv.x + 1.0f) * 0.5f * (float)(TEX_W - 1);
    float v = (uv.y + 1.0f) * 0.5f * (float)(TEX_H - 1);

    float fu0 = floorf(u);
    float fv0 = floorf(v);
    int u0 = (int)fu0;
    int v0 = (int)fv0;
    int u1 = (int)ceilf(u);   // NOT u0+1: exact-integer coords must collapse
    int v1 = (int)ceilf(v);

    float a = u - fu0;
    float b = v - fv0;
    float ia = 1.0f - a;
    float ib = 1.0f - b;

    // texture[x][y][c] flat index = (x*TEX_H + y)*3 + c  (max ~12.6M, fits int)
    const float* r0 = tex + u0 * (TEX_H * 3);
    const float* r1 = tex + u1 * (TEX_H * 3);
    int c0 = v0 * 3;
    int c1 = v1 * 3;

    float t00x = r0[c0 + 0], t00y = r0[c0 + 1], t00z = r0[c0 + 2];
    float t10x = r1[c0 + 0], t10y = r1[c0 + 1], t10z = r1[c0 + 2];
    float t01x = r0[c1 + 0], t01y = r0[c1 + 1], t01z = r0[c1 + 2];
    float t11x = r1[c1 + 0], t11y = r1[c1 + 1], t11z = r1[c1 + 2];

    // exact reference association:
    // (t00*a + t10*(1-a))*b + (t01*a + t11*(1-a))*(1-b)
    float ox = (t00x * a + t10x * ia) * b + (t01x * a + t11x * ia) * ib;
    float oy = (t00y * a + t10y * ia) * b + (t01y * a + t11y * ia) * ib;
    float oz = (t00z * a + t10z * ia) * b + (t01z * a + t11z * ia) * ib;

    out[i * 3 + 0] = ox;
    out[i * 3 + 1] = oy;
    out[i * 3 + 2] = oz;
}

extern "C" void kernel_launch(void* const* d_in, const int* in_sizes, int n_in,
                              void* d_out, int out_size, void* d_ws, size_t ws_size,
                              hipStream_t stream) {
    const float* uvs = (const float*)d_in[0];   // [N,2] f32
    const float* tex = (const float*)d_in[1];   // [2048,2048,3] f32
    float* out = (float*)d_out;                 // [N,3] f32

    int n = in_sizes[0] / 2;
    int block = 256;
    int grid = (n + block - 1) / block;
    difftex_bilinear_kernel<<<grid, block, 0, stream>>>(uvs, tex, out, n);
}